// Round 1
// baseline (11248.563 us; speedup 1.0000x reference)
//
#include <hip/hip_runtime.h>
#include <math.h>

#define NEGF   (-1e30f)
#define FINTH  (-5e29f)
#define VSZ    32000
#define KBM    5
#define BB     32
#define SEQL   34   // T+1 where T = 33

__device__ __forceinline__ bool cand_gt(float av, int ai, float bv, int bi) {
  return (av > bv) || (av == bv && ai < bi);
}

// ---------------- init ----------------
__global__ void init_kernel(float* hb0, int* word_buf, int* hsrc) {
  int i = blockIdx.x * 256 + threadIdx.x;
  if (i < 32 * 512) hb0[i] = 0.f;
  if (i < 160) { word_buf[i] = 0; hsrc[i] = i / KBM; }
}

// ---------------- gates GEMM: gi = x@Wih^T + bih, gh = h@Whh^T + bhh ----------------
// grid.x = 96 (16 j-cols each), grid.y = 0: gi, 1: gh.  P = ceil(M/32) as template.
template<int P>
__global__ __launch_bounds__(256) void gates_kernel(
    const float* __restrict__ emb, const int* __restrict__ tok_ptr, int tok_stride,
    const float* __restrict__ hbuf, const int* __restrict__ hsrc,
    const float* __restrict__ Wih, const float* __restrict__ Whh,
    const float* __restrict__ bih, const float* __restrict__ bhh,
    float* __restrict__ gi, float* __restrict__ gh, int M)
{
  const int j0 = blockIdx.x * 16;
  const bool is_h = (blockIdx.y != 0);
  const float* W    = is_h ? Whh : Wih;
  const float* bias = is_h ? bhh : bih;
  float* out        = is_h ? gh  : gi;

  __shared__ float A[160 * 36];
  __shared__ float Bw[16 * 36];

  const int tid = threadIdx.x;
  const int vg = tid & 7;    // j pair: j0 + vg*2 + {0,1}
  const int mg = tid >> 3;   // m = mg + 32*p

  float acc[2][P];
  #pragma unroll
  for (int i = 0; i < 2; i++)
    #pragma unroll
    for (int p = 0; p < P; p++) acc[i][p] = 0.f;

  for (int k0 = 0; k0 < 512; k0 += 32) {
    // stage A (M x 32)
    for (int idx = tid; idx < M * 8; idx += 256) {
      int m = idx >> 3, f = idx & 7;
      const float* rp;
      if (is_h) { int r = hsrc ? hsrc[m] : m; rp = hbuf + (long)r * 512; }
      else      { int tk = tok_ptr[m * tok_stride]; rp = emb + (long)tk * 512; }
      float4 v = *(const float4*)(rp + k0 + f * 4);
      *(float4*)&A[m * 36 + f * 4] = v;
    }
    // stage W (16 x 32)
    for (int idx = tid; idx < 16 * 8; idx += 256) {
      int j = idx >> 3, f = idx & 7;
      float4 v = *(const float4*)(W + (long)(j0 + j) * 512 + k0 + f * 4);
      *(float4*)&Bw[j * 36 + f * 4] = v;
    }
    __syncthreads();
    #pragma unroll
    for (int k = 0; k < 32; k += 4) {
      float4 w0 = *(const float4*)&Bw[(vg * 2 + 0) * 36 + k];
      float4 w1 = *(const float4*)&Bw[(vg * 2 + 1) * 36 + k];
      #pragma unroll
      for (int p = 0; p < P; p++) {
        float4 a = *(const float4*)&A[(mg + 32 * p) * 36 + k];
        acc[0][p] += a.x * w0.x + a.y * w0.y + a.z * w0.z + a.w * w0.w;
        acc[1][p] += a.x * w1.x + a.y * w1.y + a.z * w1.z + a.w * w1.w;
      }
    }
    __syncthreads();
  }
  #pragma unroll
  for (int p = 0; p < P; p++) {
    int m = mg + 32 * p;
    if (m < M) {
      int j = j0 + vg * 2;
      out[(long)m * 1536 + j + 0] = acc[0][p] + bias[j + 0];
      out[(long)m * 1536 + j + 1] = acc[1][p] + bias[j + 1];
    }
  }
}

// ---------------- GRU elementwise update ----------------
__global__ __launch_bounds__(256) void hupd_kernel(
    const float* __restrict__ gi, const float* __restrict__ gh,
    const float* __restrict__ hin, const int* __restrict__ hsrc,
    float* __restrict__ hout, int M)
{
  int idx = blockIdx.x * 256 + threadIdx.x;
  if (idx >= M * 512) return;
  int m = idx >> 9, i = idx & 511;
  const float* gim = gi + (long)m * 1536;
  const float* ghm = gh + (long)m * 1536;
  float ir = gim[i], iz = gim[512 + i], inn = gim[1024 + i];
  float hr = ghm[i], hz = ghm[512 + i], hn = ghm[1024 + i];
  float r = 1.f / (1.f + expf(-(ir + hr)));
  float z = 1.f / (1.f + expf(-(iz + hz)));
  float n = tanhf(inn + r * hn);
  int src = hsrc ? hsrc[m] : m;
  float h = hin[(long)src * 512 + i];
  hout[(long)m * 512 + i] = (1.f - z) * n + z * h;
}

// ---------------- logits GEMM: logits = h1 @ W_out + b_out (160 x 32000, K=512) ----------------
__global__ __launch_bounds__(256) void logits_kernel(
    const float* __restrict__ h1, const float* __restrict__ Wout,
    const float* __restrict__ bout, float* __restrict__ logits)
{
  const int v0 = blockIdx.x * 64;
  __shared__ float A[160 * 36];
  __shared__ float Bw[64 * 36];   // [v][k]
  const int tid = threadIdx.x;
  const int vg = tid & 15;        // v = v0 + vg*4 + i
  const int mg = tid >> 4;        // m = mg + 16*p

  float acc[10][4];
  #pragma unroll
  for (int p = 0; p < 10; p++)
    #pragma unroll
    for (int i = 0; i < 4; i++) acc[p][i] = 0.f;

  for (int k0 = 0; k0 < 512; k0 += 32) {
    for (int idx = tid; idx < 160 * 8; idx += 256) {
      int m = idx >> 3, f = idx & 7;
      *(float4*)&A[m * 36 + f * 4] = *(const float4*)(h1 + (long)m * 512 + k0 + f * 4);
    }
    for (int idx = tid; idx < 32 * 16; idx += 256) {
      int k = idx >> 4, f = idx & 15;
      float4 w = *(const float4*)(Wout + (long)(k0 + k) * VSZ + v0 + f * 4);
      Bw[(f * 4 + 0) * 36 + k] = w.x;
      Bw[(f * 4 + 1) * 36 + k] = w.y;
      Bw[(f * 4 + 2) * 36 + k] = w.z;
      Bw[(f * 4 + 3) * 36 + k] = w.w;
    }
    __syncthreads();
    #pragma unroll
    for (int k = 0; k < 32; k += 4) {
      float4 w[4];
      #pragma unroll
      for (int i = 0; i < 4; i++) w[i] = *(const float4*)&Bw[(vg * 4 + i) * 36 + k];
      #pragma unroll
      for (int p = 0; p < 10; p++) {
        float4 a = *(const float4*)&A[(mg + 16 * p) * 36 + k];
        #pragma unroll
        for (int i = 0; i < 4; i++)
          acc[p][i] += a.x * w[i].x + a.y * w[i].y + a.z * w[i].z + a.w * w[i].w;
      }
    }
    __syncthreads();
  }
  float4 bo = *(const float4*)&bout[v0 + vg * 4];
  #pragma unroll
  for (int p = 0; p < 10; p++) {
    int m = mg + 16 * p;
    float4 r;
    r.x = acc[p][0] + bo.x; r.y = acc[p][1] + bo.y;
    r.z = acc[p][2] + bo.z; r.w = acc[p][3] + bo.w;
    *(float4*)&logits[(long)m * VSZ + v0 + vg * 4] = r;
  }
}

// ---------------- logsumexp per row ----------------
__global__ __launch_bounds__(256) void lse_kernel(const float* __restrict__ logits,
                                                  float* __restrict__ lse)
{
  int row = blockIdx.x;
  const float4* x4 = (const float4*)(logits + (long)row * VSZ);
  float m = -3.4e38f, s = 0.f;
  for (int i = threadIdx.x; i < VSZ / 4; i += 256) {
    float4 v = x4[i];
    float vm = fmaxf(fmaxf(v.x, v.y), fmaxf(v.z, v.w));
    if (vm > m) { s *= expf(m - vm); m = vm; }
    s += expf(v.x - m) + expf(v.y - m) + expf(v.z - m) + expf(v.w - m);
  }
  for (int mask = 1; mask < 64; mask <<= 1) {
    float om = __shfl_xor(m, mask, 64);
    float os = __shfl_xor(s, mask, 64);
    float nm = fmaxf(m, om);
    s = s * expf(m - nm) + os * expf(om - nm);
    m = nm;
  }
  __shared__ float sm[4], ss[4];
  int tid = threadIdx.x;
  if ((tid & 63) == 0) { sm[tid >> 6] = m; ss[tid >> 6] = s; }
  __syncthreads();
  if (tid == 0) {
    float M2 = sm[0], S2 = ss[0];
    for (int w = 1; w < 4; w++) {
      float nm = fmaxf(M2, sm[w]);
      S2 = S2 * expf(M2 - nm) + ss[w] * expf(sm[w] - nm);
      M2 = nm;
    }
    lse[row] = M2 + logf(S2);
  }
}

// ---------------- top-5 over (kcount x V) per sentence ----------------
__global__ __launch_bounds__(256) void topk_kernel(
    const float* __restrict__ logits, const float* __restrict__ lse,
    const float* __restrict__ act_ll, float* __restrict__ vals5,
    int* __restrict__ idx5, int kcount)
{
  int b = blockIdx.x, tid = threadIdx.x;
  float tv0 = -3.4e38f, tv1 = -3.4e38f, tv2 = -3.4e38f, tv3 = -3.4e38f, tv4 = -3.4e38f;
  int ti0 = 0x7fffffff, ti1 = 0x7fffffff, ti2 = 0x7fffffff, ti3 = 0x7fffffff, ti4 = 0x7fffffff;

#define INS5(xx, ii)                                                           \
  if (cand_gt(xx, ii, tv4, ti4)) {                                             \
    tv4 = xx; ti4 = ii;                                                        \
    if (cand_gt(tv4, ti4, tv3, ti3)) { float tf = tv3; int tj = ti3; tv3 = tv4; ti3 = ti4; tv4 = tf; ti4 = tj; \
      if (cand_gt(tv3, ti3, tv2, ti2)) { tf = tv2; tj = ti2; tv2 = tv3; ti2 = ti3; tv3 = tf; ti3 = tj; \
        if (cand_gt(tv2, ti2, tv1, ti1)) { tf = tv1; tj = ti1; tv1 = tv2; ti1 = ti2; tv2 = tf; ti2 = tj; \
          if (cand_gt(tv1, ti1, tv0, ti0)) { tf = tv0; tj = ti0; tv0 = tv1; ti0 = ti1; tv1 = tf; ti1 = tj; } } } } }

  for (int k = 0; k < kcount; k++) {
    int row = b * KBM + k;
    float a = (kcount == 1) ? 0.f : act_ll[row];
    float l = lse[row];
    const float4* lg4 = (const float4*)(logits + (long)row * VSZ);
    int base = k * VSZ;
    for (int v4 = tid; v4 < VSZ / 4; v4 += 256) {
      float4 c = lg4[v4];
      int id0 = base + v4 * 4;
      float x0 = a + (c.x - l); INS5(x0, id0);
      float x1 = a + (c.y - l); INS5(x1, id0 + 1);
      float x2 = a + (c.z - l); INS5(x2, id0 + 2);
      float x3 = a + (c.w - l); INS5(x3, id0 + 3);
    }
  }
  __shared__ float sv[256 * 5];
  __shared__ int   si[256 * 5];
  sv[tid * 5 + 0] = tv0; si[tid * 5 + 0] = ti0;
  sv[tid * 5 + 1] = tv1; si[tid * 5 + 1] = ti1;
  sv[tid * 5 + 2] = tv2; si[tid * 5 + 2] = ti2;
  sv[tid * 5 + 3] = tv3; si[tid * 5 + 3] = ti3;
  sv[tid * 5 + 4] = tv4; si[tid * 5 + 4] = ti4;
  __syncthreads();
  for (int str = 128; str >= 1; str >>= 1) {
    if (tid < str) {
      float* av = &sv[tid * 5];         int* ai = &si[tid * 5];
      float* bv = &sv[(tid + str) * 5]; int* bi = &si[(tid + str) * 5];
      float o0[5]; int o1[5];
      int i = 0, j = 0;
      #pragma unroll
      for (int o = 0; o < 5; o++) {
        float avv = av[i]; int aii = ai[i];
        float bvv = bv[j]; int bii = bi[j];
        bool ta = cand_gt(avv, aii, bvv, bii);
        o0[o] = ta ? avv : bvv; o1[o] = ta ? aii : bii;
        i += ta ? 1 : 0; j += ta ? 0 : 1;
      }
      #pragma unroll
      for (int o = 0; o < 5; o++) { av[o] = o0[o]; ai[o] = o1[o]; }
    }
    __syncthreads();
  }
  if (tid == 0) {
    #pragma unroll
    for (int o = 0; o < 5; o++) { vals5[b * 5 + o] = sv[o]; idx5[b * 5 + o] = si[o]; }
  }
}

// ---------------- step-0 bookkeeping ----------------
__global__ void book0_kernel(const float* __restrict__ vals5, const int* __restrict__ idx5,
                             int* __restrict__ seqs, float* __restrict__ act_ll,
                             int* __restrict__ word_buf, int* __restrict__ hsrc,
                             float* __restrict__ best_ll, int* __restrict__ best_seq)
{
  int b = blockIdx.x, tid = threadIdx.x;
  if (tid < SEQL) {
    for (int j = 0; j < KBM; j++) {
      int w = idx5[b * 5 + j];
      seqs[(b * KBM + j) * SEQL + tid] = (tid == 0) ? 0 : (tid == 1 ? w : 2);
    }
    best_seq[b * SEQL + tid] = 2;
  }
  if (tid < KBM) {
    act_ll[b * KBM + tid] = vals5[b * 5 + tid];
    word_buf[b * KBM + tid] = idx5[b * 5 + tid];
    hsrc[b * KBM + tid] = b * KBM + tid;
  }
  if (tid == 0) best_ll[b] = NEGF;
}

// ---------------- per-step bookkeeping ----------------
__global__ void book_kernel(const float* __restrict__ vals5, const int* __restrict__ idx5,
                            const int* __restrict__ seqs_old, int* __restrict__ seqs_new,
                            float* __restrict__ act_ll, int* __restrict__ word_buf,
                            int* __restrict__ hsrc, float* __restrict__ best_ll,
                            int* __restrict__ best_seq, int t)
{
  int b = blockIdx.x, tid = threadIdx.x;
  __shared__ int ls[KBM][SEQL];
  float v[KBM]; int pr[KBM], wd[KBM];
  #pragma unroll
  for (int j = 0; j < KBM; j++) {
    v[j] = vals5[b * 5 + j];
    int id = idx5[b * 5 + j];
    pr[j] = id / VSZ; wd[j] = id % VSZ;
  }
  #pragma unroll
  for (int j = 0; j < KBM; j++) {
    if (tid < SEQL) {
      int x = (tid == t + 1) ? wd[j] : seqs_old[(b * KBM + pr[j]) * SEQL + tid];
      ls[j][tid] = x;
      seqs_new[(b * KBM + j) * SEQL + tid] = x;
    }
  }
  __syncthreads();
  float cll[KBM];
  #pragma unroll
  for (int j = 0; j < KBM; j++) {
    bool fin = v[j] > FINTH;
    bool eos = (wd[j] == 1) && fin;
    cll[j] = eos ? v[j] / (float)(t + 2) : NEGF;
  }
  int jb = 0; float cb = cll[0];
  #pragma unroll
  for (int j = 1; j < KBM; j++) if (cll[j] > cb) { cb = cll[j]; jb = j; }
  bool improve = cb > best_ll[b];
  if (improve) {
    if (tid == 0) best_ll[b] = cb;
    if (tid < SEQL) best_seq[b * SEQL + tid] = ls[jb][tid];
  }
  if (tid < KBM) {
    int j = tid;
    bool fin = v[j] > FINTH;
    bool eos = (wd[j] == 1) && fin;
    act_ll[b * KBM + j] = (fin && !eos) ? v[j] : NEGF;
    word_buf[b * KBM + j] = wd[j];
    hsrc[b * KBM + j] = b * KBM + pr[j];
  }
}

// ---------------- winner selection ----------------
__global__ void final_kernel(const float* __restrict__ best_ll, const int* __restrict__ best_seq,
                             const float* __restrict__ act_ll, const int* __restrict__ seqs,
                             int* __restrict__ out)
{
  int b = blockIdx.x, tid = threadIdx.x;
  bool have = best_ll[b] > FINTH;
  int jb = 0; float ab = act_ll[b * KBM];
  for (int j = 1; j < KBM; j++)
    if (act_ll[b * KBM + j] > ab) { ab = act_ll[b * KBM + j]; jb = j; }
  if (tid < SEQL)
    out[b * SEQL + tid] = have ? best_seq[b * SEQL + tid]
                               : seqs[(b * KBM + jb) * SEQL + tid];
}

extern "C" void kernel_launch(void* const* d_in, const int* in_sizes, int n_in,
                              void* d_out, int out_size, void* d_ws, size_t ws_size,
                              hipStream_t stream)
{
  const int*   source  = (const int*)d_in[0];
  const float* emb_src = (const float*)d_in[1];
  const float* emb_tgt = (const float*)d_in[2];
  const float* eWih = (const float*)d_in[3];
  const float* eWhh = (const float*)d_in[4];
  const float* ebih = (const float*)d_in[5];
  const float* ebhh = (const float*)d_in[6];
  const float* dWih = (const float*)d_in[7];
  const float* dWhh = (const float*)d_in[8];
  const float* dbih = (const float*)d_in[9];
  const float* dbhh = (const float*)d_in[10];
  const float* Wout = (const float*)d_in[11];
  const float* bout = (const float*)d_in[12];
  int* out = (int*)d_out;

  char* ws = (char*)d_ws;
  size_t off = 0;
  auto alloc = [&](size_t bytes) {
    void* p = ws + off;
    off = (off + bytes + 255) & ~(size_t)255;
    return p;
  };
  float* hb0     = (float*)alloc(160 * 512 * 4);
  float* hb1     = (float*)alloc(160 * 512 * 4);
  float* gi      = (float*)alloc(160 * 1536 * 4);
  float* gh      = (float*)alloc(160 * 1536 * 4);
  float* logits  = (float*)alloc((size_t)160 * VSZ * 4);
  float* lse     = (float*)alloc(160 * 4);
  float* act_ll  = (float*)alloc(160 * 4);
  float* vals5   = (float*)alloc(160 * 4);
  float* best_ll = (float*)alloc(32 * 4);
  int*   idx5    = (int*)alloc(160 * 4);
  int*   seqs0   = (int*)alloc(160 * SEQL * 4);
  int*   seqs1   = (int*)alloc(160 * SEQL * 4);
  int*   wordb   = (int*)alloc(160 * 4);
  int*   hsrc    = (int*)alloc(160 * 4);
  int*   bseq    = (int*)alloc(32 * SEQL * 4);

  init_kernel<<<64, 256, 0, stream>>>(hb0, wordb, hsrc);

  // ---- encoder: 32 GRU steps over source tokens (M = 32) ----
  for (int s = 0; s < 32; s++) {
    gates_kernel<1><<<dim3(96, 2), 256, 0, stream>>>(
        emb_src, source + s, 32, hb0, nullptr,
        eWih, eWhh, ebih, ebhh, gi, gh, 32);
    hupd_kernel<<<64, 256, 0, stream>>>(gi, gh, hb0, nullptr, hb0, 32);
  }

  // ---- decode step 0 (initial advance) ----
  gates_kernel<5><<<dim3(96, 2), 256, 0, stream>>>(
      emb_tgt, wordb, 1, hb0, hsrc, dWih, dWhh, dbih, dbhh, gi, gh, 160);
  hupd_kernel<<<320, 256, 0, stream>>>(gi, gh, hb0, hsrc, hb1, 160);
  logits_kernel<<<500, 256, 0, stream>>>(hb1, Wout, bout, logits);
  lse_kernel<<<160, 256, 0, stream>>>(logits, lse);
  topk_kernel<<<32, 256, 0, stream>>>(logits, lse, act_ll, vals5, idx5, 1);
  book0_kernel<<<32, 64, 0, stream>>>(vals5, idx5, seqs0, act_ll, wordb, hsrc,
                                      best_ll, bseq);

  // ---- decode steps t = 1..32 ----
  float* hcur = hb1; float* hoth = hb0;
  int* scur = seqs0; int* soth = seqs1;
  for (int t = 1; t <= 32; t++) {
    gates_kernel<5><<<dim3(96, 2), 256, 0, stream>>>(
        emb_tgt, wordb, 1, hcur, hsrc, dWih, dWhh, dbih, dbhh, gi, gh, 160);
    hupd_kernel<<<320, 256, 0, stream>>>(gi, gh, hcur, hsrc, hoth, 160);
    logits_kernel<<<500, 256, 0, stream>>>(hoth, Wout, bout, logits);
    lse_kernel<<<160, 256, 0, stream>>>(logits, lse);
    topk_kernel<<<32, 256, 0, stream>>>(logits, lse, act_ll, vals5, idx5, 5);
    book_kernel<<<32, 64, 0, stream>>>(vals5, idx5, scur, soth, act_ll, wordb,
                                       hsrc, best_ll, bseq, t);
    { float* tmp = hcur; hcur = hoth; hoth = tmp; }
    { int* tmp = scur; scur = soth; soth = tmp; }
  }

  final_kernel<<<32, 64, 0, stream>>>(best_ll, bseq, act_ll, scur, out);
}